// Round 10
// baseline (667.946 us; speedup 1.0000x reference)
//
#include <hip/hip_runtime.h>
#include <hip/hip_bf16.h>
#include <cstddef>

#define B_    64
#define NPG   1024
#define F_    128
#define K_    128
#define E_    16384
#define N_    (B_*NPG)        // 65536
#define BE_   (B_*E_)         // 1048576
#define ADJ_DIM 8192
#define ADJ_ELEMS 67108864UL  // 8192*8192

typedef __bf16 bf16x8 __attribute__((ext_vector_type(8)));
typedef float  f32x4  __attribute__((ext_vector_type(4)));
typedef unsigned short u16x8 __attribute__((ext_vector_type(8)));

__device__ inline unsigned short f2b(float f) {
  __bf16 b = (__bf16)f;
  return *reinterpret_cast<unsigned short*>(&b);
}

// ---------------- W transpose+cvt: Wt[j][k] bf16 ----------------
__global__ void k_wt(const float* __restrict__ Wf, const float* __restrict__ Wp,
                     __bf16* __restrict__ Wt) {
  int j = blockIdx.x;
  int k = threadIdx.x;
  const float* W = (j < 128) ? Wf : Wp;
  int jj = j & 127;
  Wt[j * 256 + k] = (__bf16)W[k * 128 + jj];
}

// ---------------- zero M (256 MB) + deg_in counts ----------------
__global__ void k_count(const int* __restrict__ dstl, int* __restrict__ deg_in,
                        float* __restrict__ M) {
  int i = blockIdx.x * 256 + threadIdx.x;
  float4 z4 = make_float4(0.f, 0.f, 0.f, 0.f);
  float4* mz = reinterpret_cast<float4*>(M) + (size_t)blockIdx.x * 4096 + threadIdx.x;
  #pragma unroll
  for (int r = 0; r < 16; ++r) mz[r * 256] = z4;
  int b = i >> 14;
  atomicAdd(&deg_in[(b << 10) + dstl[i]], 1);
}

// ---------------- scatter edges into dense M[g][dst][src] += 1 ----------------
__global__ void k_scatterM(const int* __restrict__ srcl, const int* __restrict__ dstl,
                           float* __restrict__ M) {
  int i = blockIdx.x * 256 + threadIdx.x;
  int b = i >> 14;
  atomicAdd(&M[(size_t)b * (NPG * (size_t)NPG) + (size_t)dstl[i] * NPG + srcl[i]], 1.0f);
}

// ---------------- c = (M @ h) / deg  -> cb bf16. blk = g*8 + mt ----------------
__global__ __launch_bounds__(256) void k_cgemm(const float* __restrict__ M,
                                               const float* __restrict__ h,
                                               const int* __restrict__ deg,
                                               unsigned short* __restrict__ cb) {
  const int blk = blockIdx.x;
  const int g = blk >> 3, mt = blk & 7;
  const float* __restrict__ Mg = M + (size_t)g * NPG * NPG + (size_t)mt * 128 * NPG;
  const float* __restrict__ hg = h + (size_t)g * NPG * 128;
  __shared__ __align__(16) unsigned short Am[128 * 40];  // [m][s-chunk]
  __shared__ __align__(16) unsigned short Bt[128 * 40];  // [f][s-chunk]
  const int t = threadIdx.x;
  const int wid = t >> 6, lane = t & 63;
  const int lo = lane & 15, hi = lane >> 4;
  const int wk = wid >> 1, wf = wid & 1;
  const int ar = t >> 1, ac = (t & 1) * 16;
  const int sn = t & 31, sc0 = (t >> 5) * 16;

  f32x4 acc[4][4];
  #pragma unroll
  for (int m = 0; m < 4; ++m)
    #pragma unroll
    for (int f = 0; f < 4; ++f) acc[m][f] = (f32x4){0.f, 0.f, 0.f, 0.f};

  for (int s0 = 0; s0 < NPG; s0 += 32) {
    {
      const float* arow = Mg + (size_t)ar * NPG + s0 + ac;
      float4 v0 = *reinterpret_cast<const float4*>(arow);
      float4 v1 = *reinterpret_cast<const float4*>(arow + 4);
      float4 v2 = *reinterpret_cast<const float4*>(arow + 8);
      float4 v3 = *reinterpret_cast<const float4*>(arow + 12);
      u16x8 p0, p1;
      p0[0] = f2b(v0.x); p0[1] = f2b(v0.y); p0[2] = f2b(v0.z); p0[3] = f2b(v0.w);
      p0[4] = f2b(v1.x); p0[5] = f2b(v1.y); p0[6] = f2b(v1.z); p0[7] = f2b(v1.w);
      p1[0] = f2b(v2.x); p1[1] = f2b(v2.y); p1[2] = f2b(v2.z); p1[3] = f2b(v2.w);
      p1[4] = f2b(v3.x); p1[5] = f2b(v3.y); p1[6] = f2b(v3.z); p1[7] = f2b(v3.w);
      *reinterpret_cast<u16x8*>(Am + ar * 40 + ac) = p0;
      *reinterpret_cast<u16x8*>(Am + ar * 40 + ac + 8) = p1;
    }
    {
      const float* brow = hg + (size_t)(s0 + sn) * 128 + sc0;
      float4 w0 = *reinterpret_cast<const float4*>(brow);
      float4 w1 = *reinterpret_cast<const float4*>(brow + 4);
      float4 w2 = *reinterpret_cast<const float4*>(brow + 8);
      float4 w3 = *reinterpret_cast<const float4*>(brow + 12);
      float e[16] = {w0.x, w0.y, w0.z, w0.w, w1.x, w1.y, w1.z, w1.w,
                     w2.x, w2.y, w2.z, w2.w, w3.x, w3.y, w3.z, w3.w};
      #pragma unroll
      for (int i2 = 0; i2 < 16; ++i2) Bt[(sc0 + i2) * 40 + sn] = f2b(e[i2]);
    }
    __syncthreads();
    bf16x8 a[4], bb[4];
    #pragma unroll
    for (int m = 0; m < 4; ++m)
      a[m] = *reinterpret_cast<const bf16x8*>(Am + (wk * 64 + m * 16 + lo) * 40 + hi * 8);
    #pragma unroll
    for (int f = 0; f < 4; ++f)
      bb[f] = *reinterpret_cast<const bf16x8*>(Bt + (wf * 64 + f * 16 + lo) * 40 + hi * 8);
    #pragma unroll
    for (int m = 0; m < 4; ++m)
      #pragma unroll
      for (int f = 0; f < 4; ++f)
        acc[m][f] = __builtin_amdgcn_mfma_f32_16x16x32_bf16(a[m], bb[f], acc[m][f], 0, 0, 0);
    __syncthreads();
  }

  #pragma unroll
  for (int m = 0; m < 4; ++m)
    #pragma unroll
    for (int r = 0; r < 4; ++r) {
      int mrow = wk * 64 + m * 16 + hi * 4 + r;
      int node = g * NPG + mt * 128 + mrow;
      float inv = 1.0f / fmaxf((float)deg[node], 1.0f);
      #pragma unroll
      for (int f = 0; f < 4; ++f) {
        int fc = wf * 64 + f * 16 + lo;
        cb[(size_t)node * 128 + fc] = f2b(acc[m][f][r] * inv);
      }
    }
}

// ---------------- MFMA GEMM + fused l2norm/relu/softmax epilogue + adj-zero ----------------
__global__ __launch_bounds__(512) void k_gemm(const float* __restrict__ h,
                                              const unsigned short* __restrict__ cb,
                                              const __bf16* __restrict__ Wt,
                                              const float* __restrict__ bfeat,
                                              const float* __restrict__ bpool,
                                              __bf16* __restrict__ Z,
                                              float* __restrict__ adj) {
  // zero this block's adj slice (write-path work overlapping MFMA phase)
  {
    float4 z4 = make_float4(0.f, 0.f, 0.f, 0.f);
    float4* dst = reinterpret_cast<float4*>(adj) + (size_t)blockIdx.x * 32768 + threadIdx.x;
    #pragma unroll 8
    for (int r = 0; r < 64; ++r) dst[r * 512] = z4;
  }
  __shared__ char smem[69632];
  __bf16* A_lds = (__bf16*)smem;            // [128][32]
  __bf16* B_lds = (__bf16*)(smem + 8192);   // [256][40]
  const int t = threadIdx.x;
  const int wid = t >> 6, lane = t & 63;
  const int wm = wid >> 1, wn = wid & 1;
  const int lo = lane & 15, hi = lane >> 4;
  const int m0 = blockIdx.x * 128;

  float bias[8];
  const float* bsrc = wn ? bpool : bfeat;
  #pragma unroll
  for (int nf = 0; nf < 8; ++nf) bias[nf] = bsrc[nf * 16 + lo];

  f32x4 acc[2][8];
  #pragma unroll
  for (int mf = 0; mf < 2; ++mf)
    #pragma unroll
    for (int nf = 0; nf < 8; ++nf) acc[mf][nf] = (f32x4){0.f, 0.f, 0.f, 0.f};

  const int am = t >> 2, akq = (t & 3) * 8;
  const int bj = t >> 1, bh = (t & 1) * 16;

  for (int ks = 0; ks < 8; ++ks) {
    const int kb = ks * 32;
    if (kb < 128) {
      const float* arow = h + (size_t)(m0 + am) * 128 + kb + akq;
      float4 v0 = *reinterpret_cast<const float4*>(arow);
      float4 v1 = *reinterpret_cast<const float4*>(arow + 4);
      bf16x8 bv;
      bv[0] = (__bf16)v0.x; bv[1] = (__bf16)v0.y; bv[2] = (__bf16)v0.z; bv[3] = (__bf16)v0.w;
      bv[4] = (__bf16)v1.x; bv[5] = (__bf16)v1.y; bv[6] = (__bf16)v1.z; bv[7] = (__bf16)v1.w;
      *reinterpret_cast<bf16x8*>(A_lds + am * 32 + akq) = bv;
    } else {
      *reinterpret_cast<bf16x8*>(A_lds + am * 32 + akq) =
          *reinterpret_cast<const bf16x8*>((const __bf16*)cb + (size_t)(m0 + am) * 128 + (kb - 128) + akq);
    }
    {
      bf16x8 b0 = *reinterpret_cast<const bf16x8*>(Wt + bj * 256 + kb + bh);
      bf16x8 b1 = *reinterpret_cast<const bf16x8*>(Wt + bj * 256 + kb + bh + 8);
      *reinterpret_cast<bf16x8*>(B_lds + bj * 40 + bh) = b0;
      *reinterpret_cast<bf16x8*>(B_lds + bj * 40 + bh + 8) = b1;
    }
    __syncthreads();
    bf16x8 a[2], b[8];
    #pragma unroll
    for (int mf = 0; mf < 2; ++mf)
      a[mf] = *reinterpret_cast<const bf16x8*>(A_lds + (wm * 32 + mf * 16 + lo) * 32 + hi * 8);
    #pragma unroll
    for (int nf = 0; nf < 8; ++nf)
      b[nf] = *reinterpret_cast<const bf16x8*>(B_lds + (wn * 128 + nf * 16 + lo) * 40 + hi * 8);
    #pragma unroll
    for (int mf = 0; mf < 2; ++mf)
      #pragma unroll
      for (int nf = 0; nf < 8; ++nf)
        acc[mf][nf] = __builtin_amdgcn_mfma_f32_16x16x32_bf16(a[mf], b[nf], acc[mf][nf], 0, 0, 0);
    __syncthreads();
  }

  __bf16* obuf = (__bf16*)(smem + wid * 8704);    // per-wave [32][136]
  #pragma unroll
  for (int mf = 0; mf < 2; ++mf) {
    #pragma unroll
    for (int r = 0; r < 4; ++r) {
      float v[8];
      #pragma unroll
      for (int nf = 0; nf < 8; ++nf) v[nf] = acc[mf][nf][r] + bias[nf];
      float ss = 0.f;
      #pragma unroll
      for (int nf = 0; nf < 8; ++nf) ss += v[nf] * v[nf];
      ss += __shfl_xor(ss, 1, 64); ss += __shfl_xor(ss, 2, 64);
      ss += __shfl_xor(ss, 4, 64); ss += __shfl_xor(ss, 8, 64);
      float rn = 1.0f / fmaxf(sqrtf(ss), 1e-12f);
      #pragma unroll
      for (int nf = 0; nf < 8; ++nf) v[nf] = fmaxf(v[nf] * rn, 0.f);
      if (wn) {
        float mx = v[0];
        #pragma unroll
        for (int nf = 1; nf < 8; ++nf) mx = fmaxf(mx, v[nf]);
        mx = fmaxf(mx, __shfl_xor(mx, 1, 64)); mx = fmaxf(mx, __shfl_xor(mx, 2, 64));
        mx = fmaxf(mx, __shfl_xor(mx, 4, 64)); mx = fmaxf(mx, __shfl_xor(mx, 8, 64));
        float es = 0.f;
        #pragma unroll
        for (int nf = 0; nf < 8; ++nf) { v[nf] = __expf(v[nf] - mx); es += v[nf]; }
        es += __shfl_xor(es, 1, 64); es += __shfl_xor(es, 2, 64);
        es += __shfl_xor(es, 4, 64); es += __shfl_xor(es, 8, 64);
        float inv = 1.0f / es;
        #pragma unroll
        for (int nf = 0; nf < 8; ++nf) v[nf] *= inv;
      }
      int row = mf * 16 + hi * 4 + r;
      #pragma unroll
      for (int nf = 0; nf < 8; ++nf) obuf[row * 136 + nf * 16 + lo] = (__bf16)v[nf];
    }
  }
  __syncthreads();
  #pragma unroll
  for (int i = 0; i < 8; ++i) {
    int r = i * 4 + hi;
    bf16x8 d = *reinterpret_cast<const bf16x8*>(obuf + r * 136 + lo * 8);
    int node = m0 + wm * 32 + r;
    *reinterpret_cast<bf16x8*>(Z + (size_t)node * 256 + wn * 128 + lo * 8) = d;
  }
}

// ---------------- AS = M^T @ S -> ASb bf16. blk = g*8 + ut ----------------
__global__ __launch_bounds__(256) void k_asgemm(const float* __restrict__ M,
                                                const unsigned short* __restrict__ Zb,
                                                unsigned short* __restrict__ ASb) {
  const int blk = blockIdx.x;
  const int g = blk >> 3, ut = blk & 7;
  const float* __restrict__ Mg = M + (size_t)g * NPG * NPG;
  const unsigned short* __restrict__ Sg = Zb + (size_t)g * NPG * 256 + 128;
  __shared__ __align__(16) unsigned short AT[128 * 40];  // [u][v-chunk]
  __shared__ __align__(16) unsigned short ST[128 * 40];  // [k][v-chunk]
  const int t = threadIdx.x;
  const int wid = t >> 6, lane = t & 63;
  const int lo = lane & 15, hi = lane >> 4;
  const int wk = wid >> 1, wf = wid & 1;
  const int sn = t & 31, sc0 = (t >> 5) * 16;

  f32x4 acc[4][4];
  #pragma unroll
  for (int m = 0; m < 4; ++m)
    #pragma unroll
    for (int f = 0; f < 4; ++f) acc[m][f] = (f32x4){0.f, 0.f, 0.f, 0.f};

  for (int v0 = 0; v0 < NPG; v0 += 32) {
    {
      const float* arow = Mg + (size_t)(v0 + sn) * NPG + ut * 128 + sc0;
      float4 a0 = *reinterpret_cast<const float4*>(arow);
      float4 a1 = *reinterpret_cast<const float4*>(arow + 4);
      float4 a2 = *reinterpret_cast<const float4*>(arow + 8);
      float4 a3 = *reinterpret_cast<const float4*>(arow + 12);
      float e[16] = {a0.x, a0.y, a0.z, a0.w, a1.x, a1.y, a1.z, a1.w,
                     a2.x, a2.y, a2.z, a2.w, a3.x, a3.y, a3.z, a3.w};
      #pragma unroll
      for (int i2 = 0; i2 < 16; ++i2) AT[(sc0 + i2) * 40 + sn] = f2b(e[i2]);
    }
    {
      const unsigned short* srow = Sg + (size_t)(v0 + sn) * 256 + sc0;
      u16x8 s0v = *reinterpret_cast<const u16x8*>(srow);
      u16x8 s1v = *reinterpret_cast<const u16x8*>(srow + 8);
      #pragma unroll
      for (int i2 = 0; i2 < 8; ++i2) ST[(sc0 + i2) * 40 + sn] = s0v[i2];
      #pragma unroll
      for (int i2 = 0; i2 < 8; ++i2) ST[(sc0 + 8 + i2) * 40 + sn] = s1v[i2];
    }
    __syncthreads();
    bf16x8 a[4], bb[4];
    #pragma unroll
    for (int m = 0; m < 4; ++m)
      a[m] = *reinterpret_cast<const bf16x8*>(AT + (wk * 64 + m * 16 + lo) * 40 + hi * 8);
    #pragma unroll
    for (int f = 0; f < 4; ++f)
      bb[f] = *reinterpret_cast<const bf16x8*>(ST + (wf * 64 + f * 16 + lo) * 40 + hi * 8);
    #pragma unroll
    for (int m = 0; m < 4; ++m)
      #pragma unroll
      for (int f = 0; f < 4; ++f)
        acc[m][f] = __builtin_amdgcn_mfma_f32_16x16x32_bf16(a[m], bb[f], acc[m][f], 0, 0, 0);
    __syncthreads();
  }

  #pragma unroll
  for (int m = 0; m < 4; ++m)
    #pragma unroll
    for (int f = 0; f < 4; ++f)
      #pragma unroll
      for (int r = 0; r < 4; ++r) {
        int u = ut * 128 + wk * 64 + m * 16 + hi * 4 + r;
        int kc = wf * 64 + f * 16 + lo;
        ASb[(size_t)(g * NPG + u) * 128 + kc] = f2b(acc[m][f][r]);
      }
}

// ---------------- MFMA pool: D[k][f] = sum_n S[n][k] * X[n][f] ----------------
__global__ __launch_bounds__(256) void k_poolm(const unsigned short* __restrict__ Zb,
                                               const unsigned short* __restrict__ ASb,
                                               float* __restrict__ h_new,
                                               float* __restrict__ adj) {
  const int blk = blockIdx.x;
  const int b = blk >> 2, ch = (blk >> 1) & 1, nh = blk & 1;
  const int n0 = b * NPG + nh * 512;
  __shared__ __align__(16) unsigned short ST[128 * 40];
  __shared__ __align__(16) unsigned short XT[128 * 40];
  const int t = threadIdx.x;
  const int wid = t >> 6, lane = t & 63;
  const int lo = lane & 15, hi = lane >> 4;
  const int wk = wid >> 1, wf = wid & 1;
  const int sn = t & 31, sc0 = (t >> 5) * 16;

  f32x4 acc[4][4];
  #pragma unroll
  for (int m = 0; m < 4; ++m)
    #pragma unroll
    for (int f = 0; f < 4; ++f) acc[m][f] = (f32x4){0.f, 0.f, 0.f, 0.f};

  for (int nc = 0; nc < 512; nc += 32) {
    int n = n0 + nc + sn;
    {
      u16x8 s0 = *reinterpret_cast<const u16x8*>(Zb + (size_t)n * 256 + 128 + sc0);
      u16x8 s1 = *reinterpret_cast<const u16x8*>(Zb + (size_t)n * 256 + 128 + sc0 + 8);
      #pragma unroll
      for (int i = 0; i < 8; ++i) ST[(sc0 + i) * 40 + sn] = s0[i];
      #pragma unroll
      for (int i = 0; i < 8; ++i) ST[(sc0 + 8 + i) * 40 + sn] = s1[i];
    }
    {
      const unsigned short* xr = ch ? (ASb + (size_t)n * 128 + sc0)
                                    : (Zb + (size_t)n * 256 + sc0);
      u16x8 x0 = *reinterpret_cast<const u16x8*>(xr);
      u16x8 x1 = *reinterpret_cast<const u16x8*>(xr + 8);
      #pragma unroll
      for (int i = 0; i < 8; ++i) XT[(sc0 + i) * 40 + sn] = x0[i];
      #pragma unroll
      for (int i = 0; i < 8; ++i) XT[(sc0 + 8 + i) * 40 + sn] = x1[i];
    }
    __syncthreads();
    bf16x8 a[4], bb[4];
    #pragma unroll
    for (int m = 0; m < 4; ++m)
      a[m] = *reinterpret_cast<const bf16x8*>(ST + (wk * 64 + m * 16 + lo) * 40 + hi * 8);
    #pragma unroll
    for (int f = 0; f < 4; ++f)
      bb[f] = *reinterpret_cast<const bf16x8*>(XT + (wf * 64 + f * 16 + lo) * 40 + hi * 8);
    #pragma unroll
    for (int m = 0; m < 4; ++m)
      #pragma unroll
      for (int f = 0; f < 4; ++f)
        acc[m][f] = __builtin_amdgcn_mfma_f32_16x16x32_bf16(a[m], bb[f], acc[m][f], 0, 0, 0);
    __syncthreads();
  }

  if (ch == 0) {
    #pragma unroll
    for (int m = 0; m < 4; ++m)
      #pragma unroll
      for (int f = 0; f < 4; ++f)
        #pragma unroll
        for (int r = 0; r < 4; ++r) {
          int k = wk * 64 + m * 16 + hi * 4 + r;
          int fc = wf * 64 + f * 16 + lo;
          atomicAdd(&h_new[(size_t)(b * 128 + k) * 128 + fc], acc[m][f][r]);
        }
  } else {
    #pragma unroll
    for (int m = 0; m < 4; ++m)
      #pragma unroll
      for (int f = 0; f < 4; ++f)
        #pragma unroll
        for (int r = 0; r < 4; ++r) {
          int k = wk * 64 + m * 16 + hi * 4 + r;
          int fc = wf * 64 + f * 16 + lo;
          atomicAdd(&adj[(size_t)(b * 128 + k) * ADJ_DIM + b * 128 + fc], acc[m][f][r]);
        }
  }
}

extern "C" void kernel_launch(void* const* d_in, const int* in_sizes, int n_in,
                              void* d_out, int out_size, void* d_ws, size_t ws_size,
                              hipStream_t stream) {
  (void)in_sizes; (void)n_in; (void)out_size; (void)ws_size;
  const float* h   = (const float*)d_in[0];
  const int* srcl  = (const int*)d_in[1];
  const int* dstl  = (const int*)d_in[2];
  const float* Wf  = (const float*)d_in[3];
  const float* bfe = (const float*)d_in[4];
  const float* Wp  = (const float*)d_in[5];
  const float* bpo = (const float*)d_in[6];

  float* out   = (float*)d_out;
  float* adj   = out;                 // zeroed inside k_gemm, diagonal accumulated by k_poolm
  float* h_new = out + ADJ_ELEMS;     // zeroed by memset, accumulated by k_poolm

  char* Wp8 = (char*)d_ws;
  int* deg_in         = (int*)Wp8;                            //    256 KB
  float* M            = (float*)(Wp8 + (1UL << 20));          //    256 MB (dense adjacency counts)
  unsigned short* cb  = (unsigned short*)(Wp8 + (1UL << 20) + 268435456UL);  // 16 MB
  unsigned short* Zb  = cb + 8388608UL;                       // 32 MB
  unsigned short* ASb = Zb + 16777216UL;                      // 16 MB
  __bf16* Wt          = (__bf16*)(ASb + 8388608UL);           // 128 KB

  hipMemsetAsync(deg_in, 0, (size_t)N_ * sizeof(int), stream);
  hipMemsetAsync(h_new, 0, (size_t)B_ * K_ * F_ * sizeof(float), stream);
  k_wt<<<256, 256, 0, stream>>>(Wf, Wp, Wt);
  k_count<<<BE_ / 256, 256, 0, stream>>>(dstl, deg_in, M);
  k_scatterM<<<BE_ / 256, 256, 0, stream>>>(srcl, dstl, M);
  k_cgemm<<<512, 256, 0, stream>>>(M, h, deg_in, cb);
  k_gemm<<<512, 512, 0, stream>>>(h, cb, Wt, bfe, bpo, (__bf16*)Zb, adj);
  k_asgemm<<<512, 256, 0, stream>>>(M, Zb, ASb);
  k_poolm<<<256, 256, 0, stream>>>(Zb, ASb, h_new, adj);
}

// Round 14
// 545.191 us; speedup vs baseline: 1.2252x; 1.2252x over previous
//
#include <hip/hip_runtime.h>
#include <hip/hip_bf16.h>
#include <cstddef>

#define B_    64
#define NPG   1024
#define F_    128
#define K_    128
#define E_    16384
#define N_    (B_*NPG)        // 65536
#define BE_   (B_*E_)         // 1048576
#define ADJ_DIM 8192
#define ADJ_ELEMS 67108864UL  // 8192*8192

typedef __bf16 bf16x8 __attribute__((ext_vector_type(8)));
typedef float  f32x4  __attribute__((ext_vector_type(4)));
typedef unsigned short u16x8 __attribute__((ext_vector_type(8)));

__device__ inline unsigned short f2b(float f) {
  __bf16 b = (__bf16)f;
  return *reinterpret_cast<unsigned short*>(&b);
}
__device__ inline unsigned packbf(float x, float y) {
  return (unsigned)f2b(x) | ((unsigned)f2b(y) << 16);
}
__device__ inline void addrow(float* a, uint4 v) {
  a[0] += __uint_as_float(v.x << 16);
  a[1] += __uint_as_float(v.x & 0xffff0000u);
  a[2] += __uint_as_float(v.y << 16);
  a[3] += __uint_as_float(v.y & 0xffff0000u);
  a[4] += __uint_as_float(v.z << 16);
  a[5] += __uint_as_float(v.z & 0xffff0000u);
  a[6] += __uint_as_float(v.w << 16);
  a[7] += __uint_as_float(v.w & 0xffff0000u);
}

// ---------------- fused pre-pass: hbf | Wt | edge-count | adj-zero-A ----------------
// grid 4096 x 256
__global__ void k_pre(const float* __restrict__ h, const float* __restrict__ Wf,
                      const float* __restrict__ Wp, const int* __restrict__ srcl,
                      const int* __restrict__ dstl, unsigned short* __restrict__ hb,
                      __bf16* __restrict__ Wt, int* __restrict__ deg_in,
                      int* __restrict__ deg_out, float* __restrict__ adj) {
  const int bid = blockIdx.x, tid = threadIdx.x;
  if (bid < 2048) {
    // h -> bf16: 2,097,152 float4 total, 4 per thread
    #pragma unroll
    for (int r = 0; r < 4; ++r) {
      int i = bid * 1024 + r * 256 + tid;
      float4 v = reinterpret_cast<const float4*>(h)[i];
      ushort4 o;
      o.x = f2b(v.x); o.y = f2b(v.y); o.z = f2b(v.z); o.w = f2b(v.w);
      reinterpret_cast<ushort4*>(hb)[i] = o;
    }
  } else if (bid < 2304) {
    // Wt[j][k] = W[k][jj]
    int j = bid - 2048;
    const float* W = (j < 128) ? Wf : Wp;
    int jj = j & 127;
    Wt[j * 256 + tid] = (__bf16)W[tid * 128 + jj];
  } else if (bid < 2560) {
    // edge degree counts: 16 edges per thread
    int e0 = (bid - 2304) * 4096 + tid;
    #pragma unroll
    for (int r = 0; r < 16; ++r) {
      int i = e0 + r * 256;
      int b = i >> 14;
      int base = b << 10;
      atomicAdd(&deg_in[dstl[i] + base], 1);
      atomicAdd(&deg_out[srcl[i] + base], 1);
    }
  } else {
    // adj zero part A: float4 [0, 6291456)
    float4 z4 = make_float4(0.f, 0.f, 0.f, 0.f);
    float4* a4 = reinterpret_cast<float4*>(adj);
    size_t base = (size_t)(bid - 2560) * 4096 + tid;
    #pragma unroll
    for (int r = 0; r < 16; ++r) a4[base + r * 256] = z4;
  }
}

// ---------------- fused per-graph exclusive scans (both directions) ----------------
// grid 128 x 1024: block<64 -> in, else out
__global__ __launch_bounds__(1024) void k_scan2(const int* __restrict__ deg_in,
                                                const int* __restrict__ deg_out,
                                                int* __restrict__ off_in, int* __restrict__ cur_in,
                                                int* __restrict__ off_out, int* __restrict__ cur_out) {
  int dir = blockIdx.x >> 6, g = blockIdx.x & 63, t = threadIdx.x;
  const int* deg = dir ? deg_out : deg_in;
  int* off = dir ? off_out : off_in;
  int* cur = dir ? cur_out : cur_in;
  int v = deg[g * NPG + t];
  int lane = t & 63, wid = t >> 6;
  int x = v;
  #pragma unroll
  for (int d = 1; d < 64; d <<= 1) {
    int y = __shfl_up(x, d, 64);
    if (lane >= d) x += y;
  }
  __shared__ int wsum[16];
  if (lane == 63) wsum[wid] = x;
  __syncthreads();
  if (t < 16) {
    int s = wsum[t];
    #pragma unroll
    for (int d = 1; d < 16; d <<= 1) {
      int y = __shfl_up(s, d, 16);
      if (t >= d) s += y;
    }
    wsum[t] = s;
  }
  __syncthreads();
  int woff = wid ? wsum[wid - 1] : 0;
  int o = g * E_ + woff + x - v;
  off[g * NPG + t] = o;
  cur[g * NPG + t] = o;
}

// ---------------- CSR fill + adj-zero-B ----------------
// grid 2048 x 256
__global__ void k_build(const int* __restrict__ srcl, const int* __restrict__ dstl,
                        int* __restrict__ cur_in, int* __restrict__ cur_out,
                        int* __restrict__ ebd_src, int* __restrict__ ebs_dst,
                        float* __restrict__ adj) {
  const int bid = blockIdx.x, tid = threadIdx.x;
  // zero part B: float4 [6291456, 10485760)
  {
    float4 z4 = make_float4(0.f, 0.f, 0.f, 0.f);
    float4* a4 = reinterpret_cast<float4*>(adj);
    size_t base = 6291456UL + (size_t)bid * 2048 + tid;
    #pragma unroll
    for (int r = 0; r < 8; ++r) a4[base + r * 256] = z4;
  }
  #pragma unroll
  for (int r = 0; r < 2; ++r) {
    int i = bid * 512 + r * 256 + tid;
    int b = i >> 14;
    int base = b << 10;
    int s = srcl[i] + base, d = dstl[i] + base;
    int p = atomicAdd(&cur_in[d], 1);
    ebd_src[p] = s;
    int q = atomicAdd(&cur_out[s], 1);
    ebs_dst[q] = d;
  }
}

// ---------------- pure gather: 4 edges concurrently per wave (16-lane groups) ----------------
template<int ROWSTRIDE, bool MEAN>
__global__ void k_gather(const unsigned short* __restrict__ rows, const int* __restrict__ elist,
                         const int* __restrict__ off, const int* __restrict__ deg,
                         unsigned short* __restrict__ outb) {
  int w = threadIdx.x >> 6, lane = threadIdx.x & 63;
  int g = lane >> 4, li = lane & 15;
  int node = blockIdx.x * 4 + w;
  int o = off[node], d = deg[node];
  float acc[8];
  #pragma unroll
  for (int i = 0; i < 8; ++i) acc[i] = 0.f;
  const unsigned short* rbase = rows + li * 8;
  int e = o, end = o + d;
  while (e < end) {
    int cnt = end - e; if (cnt > 64) cnt = 64;
    int sidx = (lane < cnt) ? elist[e + lane] : 0;
    for (int t = 0; t * 4 < cnt; ++t) {
      int j = t * 4 + g;
      int s = __shfl(sidx, j, 64);
      if (j < cnt) {
        uint4 v = *reinterpret_cast<const uint4*>(rbase + (size_t)s * ROWSTRIDE);
        addrow(acc, v);
      }
    }
    e += cnt;
  }
  #pragma unroll
  for (int i = 0; i < 8; ++i) {
    acc[i] += __shfl_xor(acc[i], 16, 64);
    acc[i] += __shfl_xor(acc[i], 32, 64);
  }
  if (g == 0) {
    float sc = MEAN ? (1.0f / fmaxf((float)d, 1.0f)) : 1.0f;
    uint4 ov;
    ov.x = packbf(acc[0] * sc, acc[1] * sc);
    ov.y = packbf(acc[2] * sc, acc[3] * sc);
    ov.z = packbf(acc[4] * sc, acc[5] * sc);
    ov.w = packbf(acc[6] * sc, acc[7] * sc);
    *reinterpret_cast<uint4*>(outb + (size_t)node * 128 + li * 8) = ov;
  }
}

// ---------------- MFMA GEMM + fused epilogue + adj-zero-C ----------------
// grid 512 x 512
__global__ __launch_bounds__(512) void k_gemm(const __bf16* __restrict__ hb,
                                              const __bf16* __restrict__ cb,
                                              const __bf16* __restrict__ Wt,
                                              const float* __restrict__ bfeat,
                                              const float* __restrict__ bpool,
                                              __bf16* __restrict__ Z,
                                              float* __restrict__ adj) {
  // zero part C: float4 [10485760, 16777216)
  {
    float4 z4 = make_float4(0.f, 0.f, 0.f, 0.f);
    float4* a4 = reinterpret_cast<float4*>(adj);
    size_t base = 10485760UL + (size_t)blockIdx.x * 12288 + threadIdx.x;
    #pragma unroll 8
    for (int r = 0; r < 24; ++r) a4[base + r * 512] = z4;
  }
  __shared__ char smem[69632];
  __bf16* A_lds = (__bf16*)smem;            // [128][32]
  __bf16* B_lds = (__bf16*)(smem + 8192);   // [256][40]
  const int t = threadIdx.x;
  const int wid = t >> 6, lane = t & 63;
  const int wm = wid >> 1, wn = wid & 1;
  const int lo = lane & 15, hi = lane >> 4;
  const int m0 = blockIdx.x * 128;

  float bias[8];
  const float* bsrc = wn ? bpool : bfeat;
  #pragma unroll
  for (int nf = 0; nf < 8; ++nf) bias[nf] = bsrc[nf * 16 + lo];

  f32x4 acc[2][8];
  #pragma unroll
  for (int mf = 0; mf < 2; ++mf)
    #pragma unroll
    for (int nf = 0; nf < 8; ++nf) acc[mf][nf] = (f32x4){0.f, 0.f, 0.f, 0.f};

  const int am = t >> 2, akq = (t & 3) * 8;
  const int bj = t >> 1, bh = (t & 1) * 16;

  for (int ks = 0; ks < 8; ++ks) {
    const int kb = ks * 32;
    const __bf16* __restrict__ X = (kb < 128) ? hb : cb;
    const int kbb = kb & 127;
    *reinterpret_cast<bf16x8*>(A_lds + am * 32 + akq) =
        *reinterpret_cast<const bf16x8*>(X + (size_t)(m0 + am) * 128 + kbb + akq);
    {
      bf16x8 b0 = *reinterpret_cast<const bf16x8*>(Wt + bj * 256 + kb + bh);
      bf16x8 b1 = *reinterpret_cast<const bf16x8*>(Wt + bj * 256 + kb + bh + 8);
      *reinterpret_cast<bf16x8*>(B_lds + bj * 40 + bh) = b0;
      *reinterpret_cast<bf16x8*>(B_lds + bj * 40 + bh + 8) = b1;
    }
    __syncthreads();
    bf16x8 a[2], b[8];
    #pragma unroll
    for (int mf = 0; mf < 2; ++mf)
      a[mf] = *reinterpret_cast<const bf16x8*>(A_lds + (wm * 32 + mf * 16 + lo) * 32 + hi * 8);
    #pragma unroll
    for (int nf = 0; nf < 8; ++nf)
      b[nf] = *reinterpret_cast<const bf16x8*>(B_lds + (wn * 128 + nf * 16 + lo) * 40 + hi * 8);
    #pragma unroll
    for (int mf = 0; mf < 2; ++mf)
      #pragma unroll
      for (int nf = 0; nf < 8; ++nf)
        acc[mf][nf] = __builtin_amdgcn_mfma_f32_16x16x32_bf16(a[mf], b[nf], acc[mf][nf], 0, 0, 0);
    __syncthreads();
  }

  __bf16* obuf = (__bf16*)(smem + wid * 8704);    // per-wave [32][136]
  #pragma unroll
  for (int mf = 0; mf < 2; ++mf) {
    #pragma unroll
    for (int r = 0; r < 4; ++r) {
      float v[8];
      #pragma unroll
      for (int nf = 0; nf < 8; ++nf) v[nf] = acc[mf][nf][r] + bias[nf];
      float ss = 0.f;
      #pragma unroll
      for (int nf = 0; nf < 8; ++nf) ss += v[nf] * v[nf];
      ss += __shfl_xor(ss, 1, 64); ss += __shfl_xor(ss, 2, 64);
      ss += __shfl_xor(ss, 4, 64); ss += __shfl_xor(ss, 8, 64);
      float rn = 1.0f / fmaxf(sqrtf(ss), 1e-12f);
      #pragma unroll
      for (int nf = 0; nf < 8; ++nf) v[nf] = fmaxf(v[nf] * rn, 0.f);
      if (wn) {
        float mx = v[0];
        #pragma unroll
        for (int nf = 1; nf < 8; ++nf) mx = fmaxf(mx, v[nf]);
        mx = fmaxf(mx, __shfl_xor(mx, 1, 64)); mx = fmaxf(mx, __shfl_xor(mx, 2, 64));
        mx = fmaxf(mx, __shfl_xor(mx, 4, 64)); mx = fmaxf(mx, __shfl_xor(mx, 8, 64));
        float es = 0.f;
        #pragma unroll
        for (int nf = 0; nf < 8; ++nf) { v[nf] = __expf(v[nf] - mx); es += v[nf]; }
        es += __shfl_xor(es, 1, 64); es += __shfl_xor(es, 2, 64);
        es += __shfl_xor(es, 4, 64); es += __shfl_xor(es, 8, 64);
        float inv = 1.0f / es;
        #pragma unroll
        for (int nf = 0; nf < 8; ++nf) v[nf] *= inv;
      }
      int row = mf * 16 + hi * 4 + r;
      #pragma unroll
      for (int nf = 0; nf < 8; ++nf) obuf[row * 136 + nf * 16 + lo] = (__bf16)v[nf];
    }
  }
  __syncthreads();
  #pragma unroll
  for (int i = 0; i < 8; ++i) {
    int r = i * 4 + hi;
    bf16x8 d = *reinterpret_cast<const bf16x8*>(obuf + r * 136 + lo * 8);
    int node = m0 + wm * 32 + r;
    *reinterpret_cast<bf16x8*>(Z + (size_t)node * 256 + wn * 128 + lo * 8) = d;
  }
}

// ---------------- MFMA pool, direct store (no atomics): blk = b*2 + ch ----------------
// grid 128 x 512, contraction over all 1024 nodes
__global__ __launch_bounds__(512) void k_poolm(const unsigned short* __restrict__ Zb,
                                               const unsigned short* __restrict__ ASb,
                                               float* __restrict__ h_new,
                                               float* __restrict__ adj) {
  const int blk = blockIdx.x;
  const int b = blk >> 1, ch = blk & 1;
  const int n0 = b * NPG;
  __shared__ __align__(16) unsigned short ST[128 * 40];
  __shared__ __align__(16) unsigned short XT[128 * 40];
  const int t = threadIdx.x;
  const int wid = t >> 6, lane = t & 63;
  const int lo = lane & 15, hi = lane >> 4;
  const int wk = wid >> 2, wf = wid & 3;       // wave tile: rows [wk*64,+64), cols [wf*32,+32)
  const int sn = t & 31, sc0 = (t >> 5) * 8;   // staging: node-in-chunk, col base (16 groups x 8)

  f32x4 acc[4][2];
  #pragma unroll
  for (int m = 0; m < 4; ++m)
    #pragma unroll
    for (int f = 0; f < 2; ++f) acc[m][f] = (f32x4){0.f, 0.f, 0.f, 0.f};

  for (int nc = 0; nc < NPG; nc += 32) {
    int n = n0 + nc + sn;
    {
      u16x8 s0 = *reinterpret_cast<const u16x8*>(Zb + (size_t)n * 256 + 128 + sc0);
      #pragma unroll
      for (int i = 0; i < 8; ++i) ST[(sc0 + i) * 40 + sn] = s0[i];
    }
    {
      const unsigned short* xr = ch ? (ASb + (size_t)n * 128 + sc0)
                                    : (Zb + (size_t)n * 256 + sc0);
      u16x8 x0 = *reinterpret_cast<const u16x8*>(xr);
      #pragma unroll
      for (int i = 0; i < 8; ++i) XT[(sc0 + i) * 40 + sn] = x0[i];
    }
    __syncthreads();
    bf16x8 a[4], bb[2];
    #pragma unroll
    for (int m = 0; m < 4; ++m)
      a[m] = *reinterpret_cast<const bf16x8*>(ST + (wk * 64 + m * 16 + lo) * 40 + hi * 8);
    #pragma unroll
    for (int f = 0; f < 2; ++f)
      bb[f] = *reinterpret_cast<const bf16x8*>(XT + (wf * 32 + f * 16 + lo) * 40 + hi * 8);
    #pragma unroll
    for (int m = 0; m < 4; ++m)
      #pragma unroll
      for (int f = 0; f < 2; ++f)
        acc[m][f] = __builtin_amdgcn_mfma_f32_16x16x32_bf16(a[m], bb[f], acc[m][f], 0, 0, 0);
    __syncthreads();
  }

  #pragma unroll
  for (int m = 0; m < 4; ++m)
    #pragma unroll
    for (int f = 0; f < 2; ++f)
      #pragma unroll
      for (int r = 0; r < 4; ++r) {
        int k = wk * 64 + m * 16 + hi * 4 + r;
        int fc = wf * 32 + f * 16 + lo;
        if (ch == 0)
          h_new[(size_t)(b * 128 + k) * 128 + fc] = acc[m][f][r];
        else
          adj[(size_t)(b * 128 + k) * ADJ_DIM + b * 128 + fc] = acc[m][f][r];
      }
}

extern "C" void kernel_launch(void* const* d_in, const int* in_sizes, int n_in,
                              void* d_out, int out_size, void* d_ws, size_t ws_size,
                              hipStream_t stream) {
  (void)in_sizes; (void)n_in; (void)out_size; (void)ws_size;
  const float* h   = (const float*)d_in[0];
  const int* srcl  = (const int*)d_in[1];
  const int* dstl  = (const int*)d_in[2];
  const float* Wf  = (const float*)d_in[3];
  const float* bfe = (const float*)d_in[4];
  const float* Wp  = (const float*)d_in[5];
  const float* bpo = (const float*)d_in[6];

  float* out   = (float*)d_out;
  float* adj   = out;                 // zeroed across pre/build/gemm; diag stored by poolm
  float* h_new = out + ADJ_ELEMS;     // fully stored by poolm

  char* W = (char*)d_ws;
  int* deg_in   = (int*)W;
  int* deg_out  = deg_in + N_;
  int* off_in   = deg_out + N_;
  int* cur_in   = off_in + N_;
  int* off_out  = cur_in + N_;
  int* cur_out  = off_out + N_;
  int* ebd_src  = cur_out + N_;                     // 1,048,576
  int* ebs_dst  = ebd_src + BE_;                    // 1,048,576
  unsigned short* hb  = (unsigned short*)(ebs_dst + BE_);   //  8,388,608 bf16
  unsigned short* cb  = hb + 8388608UL;                     //  8,388,608 bf16
  unsigned short* Zb  = cb + 8388608UL;                     // 16,777,216 bf16
  unsigned short* ASb = Zb + 16777216UL;                    //  8,388,608 bf16
  __bf16* Wt          = (__bf16*)(ASb + 8388608UL);         //     65,536 bf16

  hipMemsetAsync(deg_in, 0, 2UL * N_ * sizeof(int), stream);
  k_pre<<<4096, 256, 0, stream>>>(h, Wf, Wp, srcl, dstl, hb, Wt, deg_in, deg_out, adj);
  k_scan2<<<128, 1024, 0, stream>>>(deg_in, deg_out, off_in, cur_in, off_out, cur_out);
  k_build<<<2048, 256, 0, stream>>>(srcl, dstl, cur_in, cur_out, ebd_src, ebs_dst, adj);
  k_gather<128, true><<<N_ / 4, 256, 0, stream>>>(hb, ebd_src, off_in, deg_in, cb);
  k_gemm<<<512, 512, 0, stream>>>((const __bf16*)hb, (const __bf16*)cb, Wt, bfe, bpo, (__bf16*)Zb, adj);
  k_gather<256, false><<<N_ / 4, 256, 0, stream>>>(Zb + 128, ebs_dst, off_out, deg_out, ASb);
  k_poolm<<<128, 512, 0, stream>>>(Zb, ASb, h_new, adj);
}